// Round 4
// baseline (808.478 us; speedup 1.0000x reference)
//
#include <hip/hip_runtime.h>
#include <hip/hip_bf16.h>

typedef __attribute__((ext_vector_type(8))) __bf16 bf16x8;
typedef __attribute__((ext_vector_type(4))) __bf16 bf16x4;
typedef __attribute__((ext_vector_type(16))) float f32x16;

#define D_IN   2048
#define D_FF   8192
#define D_OUT  2048
#define BATCH  4096
#define SIZE_N 5794
#define SIZE_M 2897
// padded GEMM1 dims
#define PN 5888   // 46*128
#define PK 2912   // 91*32

#define OFF_B1 16777216
#define OFF_W2 16785408
#define OFF_B2 33562624

#define BM 128
#define BN 128
#define BK 32

__device__ __forceinline__ void gload_lds16(const __bf16* g, __bf16* lds) {
    __builtin_amdgcn_global_load_lds(
        (const __attribute__((address_space(1))) void*)g,
        (__attribute__((address_space(3))) void*)lds,
        16, 0, 0);
}

// C = A (M x K, row-major) * B^T (B is N x K, row-major), bf16 in, fp32 acc.
// Inner op: v_mfma_f32_32x32x16_bf16.
// LDS swizzle (R4): 16B chunk c of row r lives at slot swapBits01(c) ^ ((r>>1)&3).
// For frag reads (window w, kgroup kh = lane>>5): slot = ((kh<<1)|w) ^ s, so the
// two half-waves differ in slot BIT1 -> disjoint bank-quad sets within every
// conflict phase grouping ({0..7}, {0..15}, {4q..4q+3}u{32+4q..}): 0 conflicts
// under any of the candidate HW phase models (R1/R2/R3 counter data fit the
// {4q}u{32+4q} grouping; this swizzle is clean under all of them).
// MODE 0: store bf16, bounds-checked, no bias
// MODE 1: +bias, relu, store bf16
// MODE 2: +bias, store fp32
template<int MODE>
__global__ __launch_bounds__(256)
void gemm_nt(const __bf16* __restrict__ A, int lda,
             const __bf16* __restrict__ B, int ldb,
             void* __restrict__ Cv, int ldc,
             const __bf16* __restrict__ bias,
             int K, int Mvalid, int Nvalid)
{
    __shared__ __bf16 As[BM * BK];
    __shared__ __bf16 Bs[BN * BK];

    const int tid  = threadIdx.x;
    const int wave = tid >> 6;
    const int lane = tid & 63;

    const int bm0 = blockIdx.x * BM;
    const int bn0 = blockIdx.y * BN;

    const int wm = (wave >> 1) * 64;   // wave's 64x64 sub-tile
    const int wn = (wave & 1) * 64;

    // staging: lane's LDS dest is fixed at wavebase + lane*16 (slot sl=lane&3 of
    // row srow=lane>>2). Fetch global chunk c = swapBits01(sl ^ s(srow)) so that
    // LDS slot sl holds swizzled content. Same 64B row per 4-lane cluster ->
    // coalescing unchanged.
    const int srow = lane >> 2;                       // 0..15
    const int tswz = (lane & 3) ^ ((lane >> 3) & 3);  // sl ^ s(srow)
    const int scol = ((((tswz & 1) << 1) | (tswz >> 1))) * 8;  // swapBits01 * 8

    const __bf16* aptr = A + (size_t)(bm0 + wave * 16 + srow) * lda + scol;
    const __bf16* bptr = B + (size_t)(bn0 + wave * 16 + srow) * ldb + scol;
    __bf16* aLds0 = &As[(wave * 16) * BK];
    __bf16* aLds1 = &As[(wave * 16 + 64) * BK];
    __bf16* bLds0 = &Bs[(wave * 16) * BK];
    __bf16* bLds1 = &Bs[(wave * 16 + 64) * BK];

    // fragment read: row = lane&31, kgroup kh = lane>>5; logical chunk for
    // K-window w is c = 2w + kh -> swapBits01(c) = (kh<<1)|w.
    const int fr = lane & 31;
    const int kh = lane >> 5;
    const int sw = (fr >> 1) & 3;
    const int fkW0 = (((kh << 1) | 0) ^ sw) * 8;   // window 0 slot (elems)
    const int fkW1 = (((kh << 1) | 1) ^ sw) * 8;   // window 1 slot

    const __bf16* aRow0 = &As[(wm + fr) * BK];
    const __bf16* aRow1 = &As[(wm + 32 + fr) * BK];
    const __bf16* bRow0 = &Bs[(wn + fr) * BK];
    const __bf16* bRow1 = &Bs[(wn + 32 + fr) * BK];

    f32x16 acc[2][2] = {};

    const int kTiles = K / BK;
    for (int kt = 0; kt < kTiles; ++kt) {
        gload_lds16(aptr,                    aLds0);
        gload_lds16(aptr + (size_t)64 * lda, aLds1);
        gload_lds16(bptr,                    bLds0);
        gload_lds16(bptr + (size_t)64 * ldb, bLds1);
        aptr += BK;
        bptr += BK;
        __builtin_amdgcn_s_waitcnt(0);
        __syncthreads();

        bf16x8 af[2][2], bfv[2][2];   // [row/col block][K-window]
        af[0][0] = *(const bf16x8*)(aRow0 + fkW0);
        af[0][1] = *(const bf16x8*)(aRow0 + fkW1);
        af[1][0] = *(const bf16x8*)(aRow1 + fkW0);
        af[1][1] = *(const bf16x8*)(aRow1 + fkW1);
        bfv[0][0] = *(const bf16x8*)(bRow0 + fkW0);
        bfv[0][1] = *(const bf16x8*)(bRow0 + fkW1);
        bfv[1][0] = *(const bf16x8*)(bRow1 + fkW0);
        bfv[1][1] = *(const bf16x8*)(bRow1 + fkW1);

        #pragma unroll
        for (int w = 0; w < 2; ++w)
            #pragma unroll
            for (int i = 0; i < 2; ++i)
                #pragma unroll
                for (int j = 0; j < 2; ++j)
                    acc[i][j] = __builtin_amdgcn_mfma_f32_32x32x16_bf16(
                        af[i][w], bfv[j][w], acc[i][j], 0, 0, 0);

        __syncthreads();
    }

    // epilogue: C/D layout col=lane&31, row=(reg&3)+8*(reg>>2)+4*(lane>>5)
    const int ecol  = lane & 31;
    const int erow0 = 4 * (lane >> 5);
    #pragma unroll
    for (int i = 0; i < 2; ++i) {
        #pragma unroll
        for (int j = 0; j < 2; ++j) {
            const int colBase = bn0 + wn + j * 32 + ecol;
            #pragma unroll
            for (int reg = 0; reg < 16; ++reg) {
                const int row = bm0 + wm + i * 32 + (reg & 3) + 8 * (reg >> 2) + erow0;
                float v = acc[i][j][reg];
                if constexpr (MODE == 0) {
                    if (row < Mvalid && colBase < Nvalid)
                        ((__bf16*)Cv)[(size_t)row * ldc + colBase] = (__bf16)v;
                } else if constexpr (MODE == 1) {
                    v += (float)bias[colBase];
                    v = v > 0.f ? v : 0.f;
                    ((__bf16*)Cv)[(size_t)row * ldc + colBase] = (__bf16)v;
                } else {
                    v += (float)bias[colBase];
                    ((float*)Cv)[(size_t)row * ldc + colBase] = v;
                }
            }
        }
    }
}

// fp32 (rows x cols) -> zero-padded bf16 (prows x pcols), row-major
__global__ void pad_cvt_bf16(const float* __restrict__ in, __bf16* __restrict__ out,
                             int rows, int cols, int pcols, int total)
{
    int idx = blockIdx.x * blockDim.x + threadIdx.x;
    if (idx >= total) return;
    int r = idx / pcols;
    int c = idx - r * pcols;
    float v = (r < rows && c < cols) ? in[(size_t)r * cols + c] : 0.0f;
    out[idx] = (__bf16)v;
}

// straight fp32 -> bf16, vectorized x4
__global__ void cvt_bf16_vec(const float4* __restrict__ in, bf16x4* __restrict__ out, int n4)
{
    int i = blockIdx.x * blockDim.x + threadIdx.x;
    if (i >= n4) return;
    float4 v = in[i];
    bf16x4 o;
    o.x = (__bf16)v.x; o.y = (__bf16)v.y; o.z = (__bf16)v.z; o.w = (__bf16)v.w;
    out[i] = o;
}

extern "C" void kernel_launch(void* const* d_in, const int* in_sizes, int n_in,
                              void* d_out, int out_size, void* d_ws, size_t ws_size,
                              hipStream_t stream)
{
    const float* x  = (const float*)d_in[0];
    const float* V1 = (const float*)d_in[1];
    const float* V2 = (const float*)d_in[2];
    float* out = (float*)d_out;

    char* ws = (char*)d_ws;
    const size_t vbElems  = (size_t)SIZE_N * SIZE_N;   // 33,570,436
    const size_t padElems = (size_t)PN * PK;           // 17,145,856

    size_t off = 0;
    __bf16* Vb = (__bf16*)(ws + off);
    off += ((vbElems * 2 + 255) / 256) * 256;          // 67,141,120
    __bf16* V1b = (__bf16*)(ws + off);                 // live only through GEMM1
    __bf16* V2b = V1b + padElems;
    __bf16* hb  = (__bf16*)(ws + off);                 // overlaps V1b/V2b (live after GEMM1)
    off += ((2 * padElems * 2 + 255) / 256) * 256;     // 68,583,424
    __bf16* xb = (__bf16*)(ws + off);
    off += (size_t)BATCH * D_IN * 2;
    if (ws_size < off) return;  // workspace too small -> fail validation cleanly

    // fp32 -> bf16 conversions (V1/V2 zero-padded to PN x PK)
    {
        int total  = (int)padElems;
        int blocks = (total + 255) / 256;
        pad_cvt_bf16<<<blocks, 256, 0, stream>>>(V1, V1b, SIZE_N, SIZE_M, PK, total);
        pad_cvt_bf16<<<blocks, 256, 0, stream>>>(V2, V2b, SIZE_N, SIZE_M, PK, total);
        int n4 = BATCH * D_IN / 4;
        cvt_bf16_vec<<<(n4 + 255) / 256, 256, 0, stream>>>((const float4*)x, (bf16x4*)xb, n4);
    }

    // GEMM1: V = V1 * V2^T  (padded 5888x5888x2912, store valid 5794x5794 as bf16 flat)
    gemm_nt<0><<<dim3(PN / BM, PN / BN), 256, 0, stream>>>(
        V1b, PK, V2b, PK, (void*)Vb, SIZE_N, (const __bf16*)nullptr, PK, SIZE_N, SIZE_N);

    // GEMM2: h = relu(x * W1^T + b1)   (4096 x 8192 x 2048)
    gemm_nt<1><<<dim3(BATCH / BM, D_FF / BN), 256, 0, stream>>>(
        xb, D_IN, Vb, D_IN, (void*)hb, D_FF, Vb + OFF_B1, D_IN, BATCH, D_FF);

    // GEMM3: out = h * W2^T + b2       (4096 x 2048 x 8192)
    gemm_nt<2><<<dim3(BATCH / BM, D_OUT / BN), 256, 0, stream>>>(
        hb, D_FF, Vb + OFF_W2, D_FF, (void*)out, D_OUT, Vb + OFF_B2, D_FF, BATCH, D_OUT);
}

// Round 5
// 729.210 us; speedup vs baseline: 1.1087x; 1.1087x over previous
//
#include <hip/hip_runtime.h>
#include <hip/hip_bf16.h>

typedef __attribute__((ext_vector_type(8))) __bf16 bf16x8;
typedef __attribute__((ext_vector_type(4))) __bf16 bf16x4;
typedef __attribute__((ext_vector_type(16))) float f32x16;

#define D_IN   2048
#define D_FF   8192
#define D_OUT  2048
#define BATCH  4096
#define SIZE_N 5794
#define SIZE_M 2897
// padded GEMM1 dims
#define PN 5888   // 46*128
#define PK 2944   // 46*64  (BK=64 tiles)

#define OFF_B1 16777216
#define OFF_W2 16785408
#define OFF_B2 33562624

#define BM 128
#define BN 128
#define BK 64

__device__ __forceinline__ void gload_lds16(const __bf16* g, __bf16* lds) {
    __builtin_amdgcn_global_load_lds(
        (const __attribute__((address_space(1))) void*)g,
        (__attribute__((address_space(3))) void*)lds,
        16, 0, 0);
}

// C = A (M x K, row-major) * B^T (B is N x K, row-major), bf16 in, fp32 acc.
// Inner op: v_mfma_f32_32x32x16_bf16, BK=64 (16 MFMA per wave per barrier —
// 2x the matrix work per barrier-drain vs BK=32).
// LDS: row = 128 B = full bank line; 16B chunk c of row r at slot c ^ (r&7).
// Bank quad of (r, sl) = sl exactly (row term drops mod 8), so any aligned
// 8-lane group reading slots c ^ (fr&7) with fr consecutive covers all 8
// quads once -> conflict-free by construction, no phase-model assumption.
// MODE 0: store bf16, bounds-checked, no bias
// MODE 1: +bias, relu, store bf16
// MODE 2: +bias, store fp32
template<int MODE>
__global__ __launch_bounds__(256)
void gemm_nt(const __bf16* __restrict__ A, int lda,
             const __bf16* __restrict__ B, int ldb,
             void* __restrict__ Cv, int ldc,
             const __bf16* __restrict__ bias,
             int K, int Mvalid, int Nvalid)
{
    __shared__ bf16x8 As[BM * 8];   // 128 rows x 8 chunks x 16 B = 16 KB
    __shared__ bf16x8 Bs[BN * 8];

    const int tid  = threadIdx.x;
    const int wave = tid >> 6;
    const int lane = tid & 63;

    const int bm0 = blockIdx.x * BM;
    const int bn0 = blockIdx.y * BN;

    const int wm = (wave >> 1) * 64;   // wave's 64x64 sub-tile
    const int wn = (wave & 1) * 64;

    // staging: one global_load_lds covers 8 rows x 8 chunks (1 KB). Lane L
    // writes LDS chunk (row 8i+(L>>3), slot L&7); it must fetch global chunk
    // c = (L&7) ^ (L>>3) of its row so that slot sl of row r holds chunk
    // sl ^ (r&7). Each 8-lane cluster still fetches one contiguous 128 B row.
    const int srow8 = lane >> 3;                    // 0..7
    const int sc8   = ((lane & 7) ^ srow8) * 8;     // swizzled chunk (elems)

    const __bf16* aptr = A + (size_t)(bm0 + wave * 32 + srow8) * lda + sc8;
    const __bf16* bptr = B + (size_t)(bn0 + wave * 32 + srow8) * ldb + sc8;

    // fragment read: row = lane&31 (+0/+32), kgroup kh = lane>>5;
    // window w in 0..3 -> chunk c = 2w + kh at slot c ^ (fr&7).
    const int fr  = lane & 31;
    const int kh  = lane >> 5;
    const int frs = fr & 7;
    const int aRow0 = (wm + fr) * 8;
    const int aRow1 = (wm + 32 + fr) * 8;
    const int bRow0 = (wn + fr) * 8;
    const int bRow1 = (wn + 32 + fr) * 8;

    f32x16 acc[2][2] = {};

    const int kTiles = K / BK;
    for (int kt = 0; kt < kTiles; ++kt) {
        #pragma unroll
        for (int i = 0; i < 4; ++i) {
            gload_lds16(aptr + (size_t)(8 * i) * lda,
                        (__bf16*)&As[(wave * 32 + 8 * i) * 8]);
            gload_lds16(bptr + (size_t)(8 * i) * ldb,
                        (__bf16*)&Bs[(wave * 32 + 8 * i) * 8]);
        }
        aptr += BK;
        bptr += BK;
        __builtin_amdgcn_s_waitcnt(0);
        __syncthreads();

        #pragma unroll
        for (int w = 0; w < 4; ++w) {
            const int sl = (2 * w + kh) ^ frs;
            bf16x8 a0 = As[aRow0 + sl];
            bf16x8 a1 = As[aRow1 + sl];
            bf16x8 b0 = Bs[bRow0 + sl];
            bf16x8 b1 = Bs[bRow1 + sl];
            acc[0][0] = __builtin_amdgcn_mfma_f32_32x32x16_bf16(a0, b0, acc[0][0], 0, 0, 0);
            acc[0][1] = __builtin_amdgcn_mfma_f32_32x32x16_bf16(a0, b1, acc[0][1], 0, 0, 0);
            acc[1][0] = __builtin_amdgcn_mfma_f32_32x32x16_bf16(a1, b0, acc[1][0], 0, 0, 0);
            acc[1][1] = __builtin_amdgcn_mfma_f32_32x32x16_bf16(a1, b1, acc[1][1], 0, 0, 0);
        }

        __syncthreads();
    }

    // epilogue: C/D layout col=lane&31, row=(reg&3)+8*(reg>>2)+4*(lane>>5)
    const int ecol  = lane & 31;
    const int erow0 = 4 * kh;
    #pragma unroll
    for (int i = 0; i < 2; ++i) {
        #pragma unroll
        for (int j = 0; j < 2; ++j) {
            const int colBase = bn0 + wn + j * 32 + ecol;
            #pragma unroll
            for (int reg = 0; reg < 16; ++reg) {
                const int row = bm0 + wm + i * 32 + (reg & 3) + 8 * (reg >> 2) + erow0;
                float v = acc[i][j][reg];
                if constexpr (MODE == 0) {
                    if (row < Mvalid && colBase < Nvalid)
                        ((__bf16*)Cv)[(size_t)row * ldc + colBase] = (__bf16)v;
                } else if constexpr (MODE == 1) {
                    v += (float)bias[colBase];
                    v = v > 0.f ? v : 0.f;
                    ((__bf16*)Cv)[(size_t)row * ldc + colBase] = (__bf16)v;
                } else {
                    v += (float)bias[colBase];
                    ((float*)Cv)[(size_t)row * ldc + colBase] = v;
                }
            }
        }
    }
}

// fp32 (rows x cols) -> zero-padded bf16 (prows x pcols), row-major
__global__ void pad_cvt_bf16(const float* __restrict__ in, __bf16* __restrict__ out,
                             int rows, int cols, int pcols, int total)
{
    int idx = blockIdx.x * blockDim.x + threadIdx.x;
    if (idx >= total) return;
    int r = idx / pcols;
    int c = idx - r * pcols;
    float v = (r < rows && c < cols) ? in[(size_t)r * cols + c] : 0.0f;
    out[idx] = (__bf16)v;
}

// straight fp32 -> bf16, vectorized x4
__global__ void cvt_bf16_vec(const float4* __restrict__ in, bf16x4* __restrict__ out, int n4)
{
    int i = blockIdx.x * blockDim.x + threadIdx.x;
    if (i >= n4) return;
    float4 v = in[i];
    bf16x4 o;
    o.x = (__bf16)v.x; o.y = (__bf16)v.y; o.z = (__bf16)v.z; o.w = (__bf16)v.w;
    out[i] = o;
}

extern "C" void kernel_launch(void* const* d_in, const int* in_sizes, int n_in,
                              void* d_out, int out_size, void* d_ws, size_t ws_size,
                              hipStream_t stream)
{
    const float* x  = (const float*)d_in[0];
    const float* V1 = (const float*)d_in[1];
    const float* V2 = (const float*)d_in[2];
    float* out = (float*)d_out;

    char* ws = (char*)d_ws;
    const size_t vbElems  = (size_t)SIZE_N * SIZE_N;   // 33,570,436
    const size_t padElems = (size_t)PN * PK;           // 17,334,272

    size_t off = 0;
    __bf16* Vb = (__bf16*)(ws + off);
    off += ((vbElems * 2 + 255) / 256) * 256;          // 67,141,120
    __bf16* V1b = (__bf16*)(ws + off);                 // live only through GEMM1
    __bf16* V2b = V1b + padElems;
    __bf16* hb  = (__bf16*)(ws + off);                 // overlaps V1b/V2b (live after GEMM1)
    off += ((2 * padElems * 2 + 255) / 256) * 256;     // 69,337,088
    __bf16* xb = (__bf16*)(ws + off);
    off += (size_t)BATCH * D_IN * 2;
    if (ws_size < off) return;  // workspace too small -> fail validation cleanly

    // fp32 -> bf16 conversions (V1/V2 zero-padded to PN x PK)
    {
        int total  = (int)padElems;
        int blocks = (total + 255) / 256;
        pad_cvt_bf16<<<blocks, 256, 0, stream>>>(V1, V1b, SIZE_N, SIZE_M, PK, total);
        pad_cvt_bf16<<<blocks, 256, 0, stream>>>(V2, V2b, SIZE_N, SIZE_M, PK, total);
        int n4 = BATCH * D_IN / 4;
        cvt_bf16_vec<<<(n4 + 255) / 256, 256, 0, stream>>>((const float4*)x, (bf16x4*)xb, n4);
    }

    // GEMM1: V = V1 * V2^T  (padded 5888x5888x2944, store valid 5794x5794 as bf16 flat)
    gemm_nt<0><<<dim3(PN / BM, PN / BN), 256, 0, stream>>>(
        V1b, PK, V2b, PK, (void*)Vb, SIZE_N, (const __bf16*)nullptr, PK, SIZE_N, SIZE_N);

    // GEMM2: h = relu(x * W1^T + b1)   (4096 x 8192 x 2048)
    gemm_nt<1><<<dim3(BATCH / BM, D_FF / BN), 256, 0, stream>>>(
        xb, D_IN, Vb, D_IN, (void*)hb, D_FF, Vb + OFF_B1, D_IN, BATCH, D_FF);

    // GEMM3: out = h * W2^T + b2       (4096 x 2048 x 8192)
    gemm_nt<2><<<dim3(BATCH / BM, D_OUT / BN), 256, 0, stream>>>(
        hb, D_FF, Vb + OFF_W2, D_FF, (void*)out, D_OUT, Vb + OFF_B2, D_FF, BATCH, D_OUT);
}